// Round 2
// baseline (343.729 us; speedup 1.0000x reference)
//
#include <hip/hip_runtime.h>
#include <hip/hip_bf16.h>
#include <math.h>

// Problem constants (setup_inputs): B=2, S=2048, IN=512, E=512, H=8, D=64,
// window_size=256 -> hw=128, 257-key window. All float tensors are FLOAT32
// (threshold analysis round 1: no bf16 eps floor). We convert x / qkv_w / o_w
// to bf16 for MFMA, accumulate fp32, emit final output as f32.
// qkv row layout: head h at cols h*192 + {0:q, 64:k, 128:v}.

typedef __bf16 bf16x8 __attribute__((ext_vector_type(8)));
typedef float f32x4 __attribute__((ext_vector_type(4)));

__device__ __forceinline__ float bflo(unsigned u) { return __uint_as_float(u << 16); }
__device__ __forceinline__ float bfhi(unsigned u) { return __uint_as_float(u & 0xffff0000u); }

__device__ __forceinline__ unsigned short f2bf(float f) {
  unsigned u = __float_as_uint(f);
  unsigned r = u + 0x7FFFu + ((u >> 16) & 1u);  // RNE; inputs are finite
  return (unsigned short)(r >> 16);
}

// Convert three f32 arrays to bf16 (packed). All n% 4 == 0. One float4/thread.
__global__ __launch_bounds__(256) void cvt3_kernel(
    const float* __restrict__ s0, unsigned short* __restrict__ d0, int n0,
    const float* __restrict__ s1, unsigned short* __restrict__ d1, int n1,
    const float* __restrict__ s2, unsigned short* __restrict__ d2, int n2) {
  int i4 = blockIdx.x * 256 + threadIdx.x;
  const int c0 = n0 >> 2, c1 = (n0 + n1) >> 2, c2 = (n0 + n1 + n2) >> 2;
  const float* s; unsigned short* d; int base4;
  if (i4 < c0)      { s = s0; d = d0; base4 = i4; }
  else if (i4 < c1) { s = s1; d = d1; base4 = i4 - c0; }
  else if (i4 < c2) { s = s2; d = d2; base4 = i4 - c1; }
  else return;
  float4 v = ((const float4*)s)[base4];
  ushort4 o;
  o.x = f2bf(v.x); o.y = f2bf(v.y); o.z = f2bf(v.z); o.w = f2bf(v.w);
  ((ushort4*)d)[base4] = o;
}

__device__ __forceinline__ void storeC(float* C, size_t i, float v) { C[i] = v; }
__device__ __forceinline__ void storeC(__hip_bfloat16* C, size_t i, float v) {
  C[i] = __float2bfloat16(v);
}

// C(M,N) = A(M,K) @ Bw(N,K)^T + bias ; bf16 in, fp32 accumulate via MFMA.
// QSCALE: multiply columns with (n%192)<64 by 0.125 (q pre-scale by 1/sqrt(D)).
// Requires M%128==0, N%128==0, K%32==0.
template <bool QSCALE, typename CT>
__global__ __launch_bounds__(256) void gemm_bt(
    const __hip_bfloat16* __restrict__ A, const __hip_bfloat16* __restrict__ Bw,
    const float* __restrict__ bias, CT* __restrict__ C,
    int M, int N, int K) {
  // LDS tiles: 128 rows x 32 k, padded row stride 40 elems (80B) -> 16B-aligned
  // frag reads, 2-way bank aliasing only (free on CDNA4).
  __shared__ __hip_bfloat16 As[128 * 40];
  __shared__ __hip_bfloat16 Bs[128 * 40];

  const int tid = threadIdx.x;
  const int wave = tid >> 6, lane = tid & 63;
  const int m0 = blockIdx.x * 128;
  const int n0 = blockIdx.y * 128;
  const int wm = (wave >> 1) * 64;  // wave's 64x64 subtile
  const int wn = (wave & 1) * 64;

  f32x4 acc[4][4] = {};

  // staging: 256 threads x 16B covers 64 rows (32 k elems = 64B/row, 4 thr/row)
  const int r0 = tid >> 2;              // row 0..63
  const int ce = (tid & 3) * 8;         // k-element offset 0..24

  const int row_a = wm + (lane & 15);
  const int row_b = wn + (lane & 15);
  const int ko = (lane >> 4) * 8;       // k offset of this lane's frag

  for (int k0 = 0; k0 < K; k0 += 32) {
    uint4 va0 = *(const uint4*)(A + (size_t)(m0 + r0) * K + k0 + ce);
    uint4 va1 = *(const uint4*)(A + (size_t)(m0 + 64 + r0) * K + k0 + ce);
    uint4 vb0 = *(const uint4*)(Bw + (size_t)(n0 + r0) * K + k0 + ce);
    uint4 vb1 = *(const uint4*)(Bw + (size_t)(n0 + 64 + r0) * K + k0 + ce);
    __syncthreads();  // previous iter's frag reads done before overwrite
    *(uint4*)(&As[r0 * 40 + ce]) = va0;
    *(uint4*)(&As[(64 + r0) * 40 + ce]) = va1;
    *(uint4*)(&Bs[r0 * 40 + ce]) = vb0;
    *(uint4*)(&Bs[(64 + r0) * 40 + ce]) = vb1;
    __syncthreads();

    bf16x8 af[4], bf[4];
#pragma unroll
    for (int i = 0; i < 4; i++)
      af[i] = *(const bf16x8*)(&As[(row_a + i * 16) * 40 + ko]);
#pragma unroll
    for (int i = 0; i < 4; i++)
      bf[i] = *(const bf16x8*)(&Bs[(row_b + i * 16) * 40 + ko]);
#pragma unroll
    for (int mi = 0; mi < 4; mi++)
#pragma unroll
      for (int ni = 0; ni < 4; ni++)
        acc[mi][ni] = __builtin_amdgcn_mfma_f32_16x16x32_bf16(
            af[mi], bf[ni], acc[mi][ni], 0, 0, 0);
  }

  // epilogue: D[row=(lane>>4)*4+r][col=lane&15]
  const int crow = (lane >> 4) * 4;
  const int ccol = lane & 15;
#pragma unroll
  for (int mi = 0; mi < 4; mi++) {
#pragma unroll
    for (int ni = 0; ni < 4; ni++) {
      const int n = n0 + wn + ni * 16 + ccol;
      float bv = bias[n];
      float scale = 1.0f;
      if (QSCALE) scale = ((n % 192) < 64) ? 0.125f : 1.0f;
      const int mb = m0 + wm + mi * 16 + crow;
#pragma unroll
      for (int r = 0; r < 4; r++) {
        float v = (acc[mi][ni][r] + bv) * scale;
        storeC(C, (size_t)(mb + r) * N + n, v);
      }
    }
  }
}

// Sliding-window attention: one wave per (b,h,s) query row.
// qkv: (B*S, 1536) bf16, q already scaled by 0.125. Output values: (B*S, 512).
__global__ __launch_bounds__(256) void attn_kernel(
    const __hip_bfloat16* __restrict__ qkv, const int* __restrict__ pm,
    __hip_bfloat16* __restrict__ vals) {
  __shared__ float sq[4 * 64];
  __shared__ float sp[4 * 320];

  const int tid = threadIdx.x;
  const int wave = tid >> 6, lane = tid & 63;
  const int g = blockIdx.x * 4 + wave;         // global row id
  const int s = g & 2047;
  const int bh = g >> 11;
  const int b = bh >> 3, h = bh & 7;

  const __hip_bfloat16* base = qkv + (size_t)b * 2048 * 1536 + h * 192;
  const __hip_bfloat16* qrow = base + (size_t)s * 1536;

  sq[wave * 64 + lane] = __bfloat162float(qrow[lane]);
  __syncthreads();

  int t0 = s - 128; if (t0 < 0) t0 = 0;
  int t1 = s + 128; if (t1 > 2047) t1 = 2047;
  const int qm = pm[b * 2048 + s];

  float sc[5];
#pragma unroll
  for (int c = 0; c < 5; c++) {
    const int t = t0 + c * 64 + lane;
    const bool inb = (t <= t1);
    float scv = -3.0e38f;  // finite mask: exp(mask - mx) underflows to 0
    if (inb && pm[b * 2048 + t] != 0) {
      const uint4* kr = (const uint4*)(base + 64 + (size_t)t * 1536);
      const float4* qp = (const float4*)&sq[wave * 64];
      float dot = 0.0f;
#pragma unroll
      for (int j = 0; j < 8; j++) {
        uint4 kv = kr[j];
        float4 q0 = qp[j * 2], q1 = qp[j * 2 + 1];
        dot += q0.x * bflo(kv.x) + q0.y * bfhi(kv.x) +
               q0.z * bflo(kv.y) + q0.w * bfhi(kv.y) +
               q1.x * bflo(kv.z) + q1.y * bfhi(kv.z) +
               q1.z * bflo(kv.w) + q1.w * bfhi(kv.w);
      }
      scv = dot;
    }
    sc[c] = scv;
  }

  // wave-wide softmax over up to 257 valid slots
  float mx = fmaxf(fmaxf(fmaxf(sc[0], sc[1]), fmaxf(sc[2], sc[3])), sc[4]);
#pragma unroll
  for (int off = 1; off < 64; off <<= 1) mx = fmaxf(mx, __shfl_xor(mx, off));

  float l = 0.0f;
  float p[5];
#pragma unroll
  for (int c = 0; c < 5; c++) {
    p[c] = __expf(sc[c] - mx);  // masked slots -> 0
    l += p[c];
  }
#pragma unroll
  for (int off = 1; off < 64; off <<= 1) l += __shfl_xor(l, off);
  l = fmaxf(l, 1e-20f);

#pragma unroll
  for (int c = 0; c < 5; c++) sp[wave * 320 + c * 64 + lane] = p[c];
  __syncthreads();

  // PV: lane = d
  const int nn = t1 - t0 + 1;
  const __hip_bfloat16* vptr = base + 128 + (size_t)t0 * 1536 + lane;
  float acc = 0.0f;
  for (int i = 0; i < nn; i++) {
    acc += sp[wave * 320 + i] * __bfloat162float(vptr[(size_t)i * 1536]);
  }
  float out = acc / l;
  if (qm == 0) out = 0.0f;  // fully-masked query row -> zeros (ref: NaN->0)
  vals[(size_t)(b * 2048 + s) * 512 + h * 64 + lane] = __float2bfloat16(out);
}

extern "C" void kernel_launch(void* const* d_in, const int* in_sizes, int n_in,
                              void* d_out, int out_size, void* d_ws, size_t ws_size,
                              hipStream_t stream) {
  const float* x     = (const float*)d_in[0];   // (2,2048,512) f32
  const int*   pm    = (const int*)d_in[1];     // (2,2048) int32
  const float* qkv_w = (const float*)d_in[2];   // (1536,512) f32
  const float* qkv_b = (const float*)d_in[3];   // (1536,) f32
  const float* o_w   = (const float*)d_in[4];   // (512,512) f32
  const float* o_b   = (const float*)d_in[5];   // (512,) f32
  float* out = (float*)d_out;                   // (2,2048,512) f32

  // ws layout (bf16 elements)
  __hip_bfloat16* wsb   = (__hip_bfloat16*)d_ws;
  __hip_bfloat16* xb    = wsb;                        // 2097152
  __hip_bfloat16* wqkvb = wsb + 2097152;              // 786432
  __hip_bfloat16* wob   = wsb + 2883584;              // 262144
  __hip_bfloat16* qkv   = wsb + 3145728;              // 6291456 (4096x1536)
  __hip_bfloat16* vals  = wsb + 9437184;              // 2097152 (4096x512)

  dim3 blk(256);
  // f32 -> bf16: x, qkv_w, o_w  (total 3145728 elems, 786432 float4s)
  cvt3_kernel<<<dim3(3072), blk, 0, stream>>>(
      x, (unsigned short*)xb, 2097152,
      qkv_w, (unsigned short*)wqkvb, 786432,
      o_w, (unsigned short*)wob, 262144);
  // QKV projection: (4096x512)@(1536x512)^T, q cols pre-scaled by 1/8
  gemm_bt<true, __hip_bfloat16><<<dim3(32, 12), blk, 0, stream>>>(
      xb, wqkvb, qkv_b, qkv, 4096, 1536, 512);
  // sliding-window attention: 32768 query rows, 4 waves/block
  attn_kernel<<<dim3(8192), blk, 0, stream>>>(qkv, pm, vals);
  // output projection: (4096x512)@(512x512)^T -> f32 out
  gemm_bt<false, float><<<dim3(32, 4), blk, 0, stream>>>(
      vals, wob, o_b, out, 4096, 512, 512);
}

// Round 3
// 127.092 us; speedup vs baseline: 2.7046x; 2.7046x over previous
//
#include <hip/hip_runtime.h>
#include <hip/hip_bf16.h>
#include <math.h>

// B=2, S=2048, IN=512, E=512, H=8, D=64, window=256 -> 257-key window.
// Inputs/outputs are FLOAT32. Pipeline:
//   cvt3: x/qkv_w/o_w f32->bf16
//   gemm_qkv: x@qkv_w^T+b -> qp[bh][s][64] (q*0.125), kp[bh][s][64], vt[bh][d][2048]
//   attn_mfma: 64-query tile x 320-key span, MFMA QK^T + softmax + MFMA PV
//   gemm_out: vals@o_w^T+b -> f32 out

typedef __bf16 bf16x8 __attribute__((ext_vector_type(8)));
typedef float f32x4 __attribute__((ext_vector_type(4)));

__device__ __forceinline__ unsigned short f2bf(float f) {
  unsigned u = __float_as_uint(f);
  unsigned r = u + 0x7FFFu + ((u >> 16) & 1u);  // RNE; finite inputs
  return (unsigned short)(r >> 16);
}

// ---------------- f32 -> bf16 conversion (x, qkv_w, o_w) ----------------
__global__ __launch_bounds__(256) void cvt3_kernel(
    const float* __restrict__ s0, unsigned short* __restrict__ d0, int n0,
    const float* __restrict__ s1, unsigned short* __restrict__ d1, int n1,
    const float* __restrict__ s2, unsigned short* __restrict__ d2, int n2) {
  int i4 = blockIdx.x * 256 + threadIdx.x;
  const int c0 = n0 >> 2, c1 = (n0 + n1) >> 2, c2 = (n0 + n1 + n2) >> 2;
  const float* s; unsigned short* d; int base4;
  if (i4 < c0)      { s = s0; d = d0; base4 = i4; }
  else if (i4 < c1) { s = s1; d = d1; base4 = i4 - c0; }
  else if (i4 < c2) { s = s2; d = d2; base4 = i4 - c1; }
  else return;
  float4 v = ((const float4*)s)[base4];
  ushort4 o;
  o.x = f2bf(v.x); o.y = f2bf(v.y); o.z = f2bf(v.z); o.w = f2bf(v.w);
  ((ushort4*)d)[base4] = o;
}

// ---------------- QKV projection GEMM ----------------
// A(4096,512) @ Bw(1536,512)^T + bias. Epilogue scatters into qp/kp/vt.
__global__ __launch_bounds__(256) void gemm_qkv(
    const __hip_bfloat16* __restrict__ A, const __hip_bfloat16* __restrict__ Bw,
    const float* __restrict__ bias,
    __hip_bfloat16* __restrict__ qp, __hip_bfloat16* __restrict__ kpb,
    unsigned short* __restrict__ vtb, int M, int N, int K) {
  __shared__ __hip_bfloat16 As[128 * 40];
  __shared__ __hip_bfloat16 Bs[128 * 40];

  const int tid = threadIdx.x;
  const int wave = tid >> 6, lane = tid & 63;
  const int m0 = blockIdx.x * 128;
  const int n0 = blockIdx.y * 128;
  const int wm = (wave >> 1) * 64;
  const int wn = (wave & 1) * 64;

  f32x4 acc[4][4] = {};

  const int r0 = tid >> 2;
  const int ce = (tid & 3) * 8;
  const int row_a = wm + (lane & 15);
  const int row_b = wn + (lane & 15);
  const int ko = (lane >> 4) * 8;

  for (int k0 = 0; k0 < K; k0 += 32) {
    uint4 va0 = *(const uint4*)(A + (size_t)(m0 + r0) * K + k0 + ce);
    uint4 va1 = *(const uint4*)(A + (size_t)(m0 + 64 + r0) * K + k0 + ce);
    uint4 vb0 = *(const uint4*)(Bw + (size_t)(n0 + r0) * K + k0 + ce);
    uint4 vb1 = *(const uint4*)(Bw + (size_t)(n0 + 64 + r0) * K + k0 + ce);
    __syncthreads();
    *(uint4*)(&As[r0 * 40 + ce]) = va0;
    *(uint4*)(&As[(64 + r0) * 40 + ce]) = va1;
    *(uint4*)(&Bs[r0 * 40 + ce]) = vb0;
    *(uint4*)(&Bs[(64 + r0) * 40 + ce]) = vb1;
    __syncthreads();

    bf16x8 af[4], bf[4];
#pragma unroll
    for (int i = 0; i < 4; i++)
      af[i] = *(const bf16x8*)(&As[(row_a + i * 16) * 40 + ko]);
#pragma unroll
    for (int i = 0; i < 4; i++)
      bf[i] = *(const bf16x8*)(&Bs[(row_b + i * 16) * 40 + ko]);
#pragma unroll
    for (int mi = 0; mi < 4; mi++)
#pragma unroll
      for (int ni = 0; ni < 4; ni++)
        acc[mi][ni] = __builtin_amdgcn_mfma_f32_16x16x32_bf16(
            af[mi], bf[ni], acc[mi][ni], 0, 0, 0);
  }

  const int crow = (lane >> 4) * 4;
  const int ccol = lane & 15;
#pragma unroll
  for (int mi = 0; mi < 4; mi++) {
    const int mb = m0 + wm + mi * 16 + crow;
    const int bq = mb >> 11, sl = mb & 2047;
#pragma unroll
    for (int ni = 0; ni < 4; ni++) {
      const int n = n0 + wn + ni * 16 + ccol;
      const int h = n / 192;
      const int rem = n - h * 192;
      const int cat = rem >> 6;       // 0=q 1=k 2=v (uniform per 16-col group)
      const int d = rem & 63;
      const float bv = bias[n];
      const size_t bh = (size_t)bq * 8 + h;
      if (cat == 2) {
        ushort4 o;
        o.x = f2bf(acc[mi][ni][0] + bv);
        o.y = f2bf(acc[mi][ni][1] + bv);
        o.z = f2bf(acc[mi][ni][2] + bv);
        o.w = f2bf(acc[mi][ni][3] + bv);
        *(ushort4*)(vtb + (bh * 64 + d) * 2048 + sl) = o;  // transposed V
      } else {
        __hip_bfloat16* dst = (cat == 0) ? qp : kpb;
        const float sc = (cat == 0) ? 0.125f : 1.0f;
#pragma unroll
        for (int r = 0; r < 4; r++)
          dst[(bh * 2048 + sl + r) * 64 + d] =
              __float2bfloat16((acc[mi][ni][r] + bv) * sc);
      }
    }
  }
}

// ---------------- MFMA sliding-window attention ----------------
// block = (b,h, 64-query tile). Keys span [s0-128, s0+191] = 320 slots.
// Wave w owns q-rows [w*16, w*16+16): its window covers key tiles w..w+16.
__global__ __launch_bounds__(256) void attn_mfma(
    const __hip_bfloat16* __restrict__ qp, const __hip_bfloat16* __restrict__ kp,
    const __hip_bfloat16* __restrict__ vt, const int* __restrict__ pm,
    __hip_bfloat16* __restrict__ vals) {
  __shared__ __hip_bfloat16 sKP[320 * 72];  // K tile; later P (4x16x328, aliased)
  __shared__ int spm[320];

  const int tid = threadIdx.x, wave = tid >> 6, lane = tid & 63;
  const int bid = blockIdx.x;
  const int s0 = (bid & 31) * 64;
  const int bh = bid >> 5;
  const int b = bh >> 3, h = bh & 7;
  const int t0 = s0 - 128;
  const int cl = lane & 15;
  const int g4 = (lane >> 4) * 4;   // C-layout row base
  const int ko = (lane >> 4) * 8;   // A/B-frag k offset

  // stage K tile: 320 rows x 128B, 8 threads/row x 16B, fully coalesced
  {
    const int e = (tid & 7) * 8;
#pragma unroll
    for (int i = 0; i < 10; i++) {
      int row = (tid >> 3) + i * 32;
      int t = t0 + row; t = min(max(t, 0), 2047);
      *(uint4*)(&sKP[row * 72 + e]) =
          *(const uint4*)(kp + ((size_t)bh * 2048 + t) * 64 + e);
    }
  }
  for (int c = tid; c < 320; c += 256) {
    int t = t0 + c;
    spm[c] = (t >= 0 && t < 2048) ? pm[b * 2048 + t] : 0;
  }
  __syncthreads();

  // Q A-frags straight from global (16B/lane, L2-hot)
  const __hip_bfloat16* qrow =
      qp + ((size_t)bh * 2048 + s0 + wave * 16 + cl) * 64 + ko;
  bf16x8 aq0 = *(const bf16x8*)(qrow);
  bf16x8 aq1 = *(const bf16x8*)(qrow + 32);

  // QK^T: 17 key tiles x 2 k-steps
  f32x4 acc[17];
#pragma unroll
  for (int i = 0; i < 17; i++) {
    const int krow = (wave + i) * 16 + cl;
    bf16x8 b0 = *(const bf16x8*)(&sKP[krow * 72 + ko]);
    bf16x8 b1 = *(const bf16x8*)(&sKP[krow * 72 + ko + 32]);
    f32x4 z = {};
    z = __builtin_amdgcn_mfma_f32_16x16x32_bf16(aq0, b0, z, 0, 0, 0);
    acc[i] = __builtin_amdgcn_mfma_f32_16x16x32_bf16(aq1, b1, z, 0, 0, 0);
  }

  // mask + row max (rows g4+r of this wave's 16)
  float mrow[4] = {-3.0e38f, -3.0e38f, -3.0e38f, -3.0e38f};
#pragma unroll
  for (int i = 0; i < 17; i++) {
    const int c = (wave + i) * 16 + cl;
    const bool cm = (spm[c] != 0);
#pragma unroll
    for (int r = 0; r < 4; r++) {
      const int qr = wave * 16 + g4 + r;
      const int dlt = c - qr;
      const bool ok = cm && dlt >= 0 && dlt <= 256;
      float sv = ok ? acc[i][r] : -3.0e38f;
      acc[i][r] = sv;
      mrow[r] = fmaxf(mrow[r], sv);
    }
  }
#pragma unroll
  for (int r = 0; r < 4; r++)
#pragma unroll
    for (int off = 1; off < 16; off <<= 1)
      mrow[r] = fmaxf(mrow[r], __shfl_xor(mrow[r], off));

  float lsum[4] = {0.f, 0.f, 0.f, 0.f};
#pragma unroll
  for (int i = 0; i < 17; i++)
#pragma unroll
    for (int r = 0; r < 4; r++) {
      float p = __expf(acc[i][r] - mrow[r]);  // masked -> exact 0
      acc[i][r] = p;
      lsum[r] += p;
    }
#pragma unroll
  for (int r = 0; r < 4; r++)
#pragma unroll
    for (int off = 1; off < 16; off <<= 1)
      lsum[r] += __shfl_xor(lsum[r], off);

  __syncthreads();  // all waves done reading sK -> safe to alias P over it

  // write P (bf16) into per-wave 16x328 region
  __hip_bfloat16* sp = sKP + wave * 5248;
#pragma unroll
  for (int i = 0; i < 17; i++) {
    const int c = (wave + i) * 16 + cl;
#pragma unroll
    for (int r = 0; r < 4; r++)
      sp[(g4 + r) * 328 + c] = __float2bfloat16(acc[i][r]);
  }
  {  // zero the one extra tile the 32-aligned PV k-steps touch
    const int zt = (wave & 1) ? (wave - 1) : (wave + 17);
    const int zc = zt * 16 + cl;
#pragma unroll
    for (int r = 0; r < 4; r++)
      sp[(g4 + r) * 328 + zc] = __float2bfloat16(0.f);
  }
  __syncthreads();

  // PV: 9 k-steps of 32 keys; B-frags from transposed V in global (16B/lane)
  f32x4 oacc[4] = {};
  const int k0 = wave >> 1;  // k-step base: keys [k0*32, k0*32+288)
  const __hip_bfloat16* vbase = vt + (size_t)bh * 64 * 2048;
#pragma unroll
  for (int ks = 0; ks < 9; ks++) {
    const int kk = (k0 + ks) * 32 + ko;
    bf16x8 pa = *(const bf16x8*)(&sp[cl * 328 + kk]);
    int tv = t0 + kk; tv = min(max(tv, 0), 2040);
#pragma unroll
    for (int ni = 0; ni < 4; ni++) {
      const int d = ni * 16 + cl;
      bf16x8 vb = *(const bf16x8*)(vbase + (size_t)d * 2048 + tv);
      oacc[ni] = __builtin_amdgcn_mfma_f32_16x16x32_bf16(pa, vb, oacc[ni], 0, 0, 0);
    }
  }

  // epilogue: /l, pm-zero, store vals[s][h*64+d]
#pragma unroll
  for (int r = 0; r < 4; r++) {
    float linv = 1.0f / fmaxf(lsum[r], 1e-20f);
    const int qrow = wave * 16 + g4 + r;
    if (spm[qrow + 128] == 0) linv = 0.0f;  // fully-masked query -> 0
    const size_t obase = ((size_t)(b * 2048 + s0 + qrow)) * 512 + h * 64 + cl;
#pragma unroll
    for (int ni = 0; ni < 4; ni++)
      vals[obase + ni * 16] = __float2bfloat16(oacc[ni][r] * linv);
  }
}

// ---------------- output projection GEMM (f32 out) ----------------
__global__ __launch_bounds__(256) void gemm_out(
    const __hip_bfloat16* __restrict__ A, const __hip_bfloat16* __restrict__ Bw,
    const float* __restrict__ bias, float* __restrict__ C,
    int M, int N, int K) {
  __shared__ __hip_bfloat16 As[128 * 40];
  __shared__ __hip_bfloat16 Bs[128 * 40];

  const int tid = threadIdx.x;
  const int wave = tid >> 6, lane = tid & 63;
  const int m0 = blockIdx.x * 128;
  const int n0 = blockIdx.y * 128;
  const int wm = (wave >> 1) * 64;
  const int wn = (wave & 1) * 64;

  f32x4 acc[4][4] = {};
  const int r0 = tid >> 2;
  const int ce = (tid & 3) * 8;
  const int row_a = wm + (lane & 15);
  const int row_b = wn + (lane & 15);
  const int ko = (lane >> 4) * 8;

  for (int k0 = 0; k0 < K; k0 += 32) {
    uint4 va0 = *(const uint4*)(A + (size_t)(m0 + r0) * K + k0 + ce);
    uint4 va1 = *(const uint4*)(A + (size_t)(m0 + 64 + r0) * K + k0 + ce);
    uint4 vb0 = *(const uint4*)(Bw + (size_t)(n0 + r0) * K + k0 + ce);
    uint4 vb1 = *(const uint4*)(Bw + (size_t)(n0 + 64 + r0) * K + k0 + ce);
    __syncthreads();
    *(uint4*)(&As[r0 * 40 + ce]) = va0;
    *(uint4*)(&As[(64 + r0) * 40 + ce]) = va1;
    *(uint4*)(&Bs[r0 * 40 + ce]) = vb0;
    *(uint4*)(&Bs[(64 + r0) * 40 + ce]) = vb1;
    __syncthreads();

    bf16x8 af[4], bf[4];
#pragma unroll
    for (int i = 0; i < 4; i++)
      af[i] = *(const bf16x8*)(&As[(row_a + i * 16) * 40 + ko]);
#pragma unroll
    for (int i = 0; i < 4; i++)
      bf[i] = *(const bf16x8*)(&Bs[(row_b + i * 16) * 40 + ko]);
#pragma unroll
    for (int mi = 0; mi < 4; mi++)
#pragma unroll
      for (int ni = 0; ni < 4; ni++)
        acc[mi][ni] = __builtin_amdgcn_mfma_f32_16x16x32_bf16(
            af[mi], bf[ni], acc[mi][ni], 0, 0, 0);
  }

  const int crow = (lane >> 4) * 4;
  const int ccol = lane & 15;
#pragma unroll
  for (int mi = 0; mi < 4; mi++) {
#pragma unroll
    for (int ni = 0; ni < 4; ni++) {
      const int n = n0 + wn + ni * 16 + ccol;
      const float bv = bias[n];
      const int mb = m0 + wm + mi * 16 + crow;
#pragma unroll
      for (int r = 0; r < 4; r++)
        C[(size_t)(mb + r) * N + n] = acc[mi][ni][r] + bv;
    }
  }
}

extern "C" void kernel_launch(void* const* d_in, const int* in_sizes, int n_in,
                              void* d_out, int out_size, void* d_ws, size_t ws_size,
                              hipStream_t stream) {
  const float* x     = (const float*)d_in[0];   // (2,2048,512)
  const int*   pm    = (const int*)d_in[1];     // (2,2048)
  const float* qkv_w = (const float*)d_in[2];   // (1536,512)
  const float* qkv_b = (const float*)d_in[3];   // (1536,)
  const float* o_w   = (const float*)d_in[4];   // (512,512)
  const float* o_b   = (const float*)d_in[5];   // (512,)
  float* out = (float*)d_out;                   // (2,2048,512)

  __hip_bfloat16* wsb   = (__hip_bfloat16*)d_ws;
  __hip_bfloat16* xb    = wsb;               // 2097152
  __hip_bfloat16* wqkvb = wsb + 2097152;     // 786432
  __hip_bfloat16* wob   = wsb + 2883584;     // 262144
  __hip_bfloat16* qp    = wsb + 3145728;     // 2097152  [bh][s][64] (scaled)
  __hip_bfloat16* kp    = wsb + 5242880;     // 2097152  [bh][s][64]
  __hip_bfloat16* vt    = wsb + 7340032;     // 2097152  [bh][d][2048]
  __hip_bfloat16* vals  = wsb + 9437184;     // 2097152  [s][512]

  dim3 blk(256);
  cvt3_kernel<<<dim3(3072), blk, 0, stream>>>(
      x, (unsigned short*)xb, 2097152,
      qkv_w, (unsigned short*)wqkvb, 786432,
      o_w, (unsigned short*)wob, 262144);
  gemm_qkv<<<dim3(32, 12), blk, 0, stream>>>(
      xb, wqkvb, qkv_b, qp, kp, (unsigned short*)vt, 4096, 1536, 512);
  attn_mfma<<<dim3(512), blk, 0, stream>>>(qp, kp, vt, pm, vals);
  gemm_out<<<dim3(32, 4), blk, 0, stream>>>(vals, wob, o_b, out, 4096, 512, 512);
}

// Round 4
// 118.892 us; speedup vs baseline: 2.8911x; 1.0690x over previous
//
#include <hip/hip_runtime.h>
#include <hip/hip_bf16.h>
#include <math.h>

// B=2, S=2048, IN=512, E=512, H=8, D=64, window=256 -> 257-key window.
// f32 in/out. cvt3 -> gemm_qkv (global_load_lds staging; q scaled by
// 0.125*log2e for exp2-domain softmax; V written transposed) -> attn_mfma
// (64q x 320k tile, QK^T/PV on MFMA, exp2 softmax, boundary-only window
// masks) -> gemm_out (64x128 tiles, 256 blocks).

typedef __bf16 bf16x8 __attribute__((ext_vector_type(8)));
typedef float f32x4 __attribute__((ext_vector_type(4)));

__device__ __forceinline__ unsigned short f2bf(float f) {
  unsigned u = __float_as_uint(f);
  unsigned r = u + 0x7FFFu + ((u >> 16) & 1u);  // RNE; finite inputs
  return (unsigned short)(r >> 16);
}

// async global->LDS DMA, 16B per lane; lds dest = wave-uniform base + lane*16
__device__ __forceinline__ void ldsdma16(void* lds, const void* g) {
  __builtin_amdgcn_global_load_lds(
      (const __attribute__((address_space(1))) unsigned int*)g,
      (__attribute__((address_space(3))) unsigned int*)lds, 16, 0, 0);
}

// ---------------- f32 -> bf16 conversion (x, qkv_w, o_w) ----------------
__global__ __launch_bounds__(256) void cvt3_kernel(
    const float* __restrict__ s0, unsigned short* __restrict__ d0, int n0,
    const float* __restrict__ s1, unsigned short* __restrict__ d1, int n1,
    const float* __restrict__ s2, unsigned short* __restrict__ d2, int n2) {
  int i4 = blockIdx.x * 256 + threadIdx.x;
  const int c0 = n0 >> 2, c1 = (n0 + n1) >> 2, c2 = (n0 + n1 + n2) >> 2;
  const float* s; unsigned short* d; int base4;
  if (i4 < c0)      { s = s0; d = d0; base4 = i4; }
  else if (i4 < c1) { s = s1; d = d1; base4 = i4 - c0; }
  else if (i4 < c2) { s = s2; d = d2; base4 = i4 - c1; }
  else return;
  float4 v = ((const float4*)s)[base4];
  ushort4 o;
  o.x = f2bf(v.x); o.y = f2bf(v.y); o.z = f2bf(v.z); o.w = f2bf(v.w);
  ((ushort4*)d)[base4] = o;
}

// ---------------- QKV projection GEMM (128x128 tile, lds-dma) ----------------
// A(4096,512) @ Bw(1536,512)^T + bias -> qp (q * 0.125*log2e), kp, vt (transposed)
__global__ __launch_bounds__(256) void gemm_qkv(
    const __hip_bfloat16* __restrict__ A, const __hip_bfloat16* __restrict__ Bw,
    const float* __restrict__ bias,
    __hip_bfloat16* __restrict__ qp, __hip_bfloat16* __restrict__ kpb,
    unsigned short* __restrict__ vtb) {
  __shared__ __hip_bfloat16 As[128 * 32];  // 64B/row, contiguous (dma layout)
  __shared__ __hip_bfloat16 Bs[128 * 32];

  const int tid = threadIdx.x, wave = tid >> 6, lane = tid & 63;
  const int m0 = blockIdx.x * 128, n0 = blockIdx.y * 128;
  const int wm = (wave >> 1) * 64, wn = (wave & 1) * 64;
  const int cl = lane & 15, ko = (lane >> 4) * 8;
  const int srow = wave * 16 + (lane >> 2);  // dma source row
  const int scol = (lane & 3) * 8;           // dma source k-offset

  f32x4 acc[4][4] = {};

  for (int k0 = 0; k0 < 512; k0 += 32) {
    __syncthreads();  // prev iter frag reads done
    ldsdma16(&As[wave * 512],        A  + (size_t)(m0 + srow) * 512 + k0 + scol);
    ldsdma16(&As[2048 + wave * 512], A  + (size_t)(m0 + 64 + srow) * 512 + k0 + scol);
    ldsdma16(&Bs[wave * 512],        Bw + (size_t)(n0 + srow) * 512 + k0 + scol);
    ldsdma16(&Bs[2048 + wave * 512], Bw + (size_t)(n0 + 64 + srow) * 512 + k0 + scol);
    __syncthreads();  // vmcnt(0) drain + barrier -> LDS ready

    bf16x8 af[4], bf[4];
#pragma unroll
    for (int i = 0; i < 4; i++)
      af[i] = *(const bf16x8*)(&As[(wm + cl + i * 16) * 32 + ko]);
#pragma unroll
    for (int i = 0; i < 4; i++)
      bf[i] = *(const bf16x8*)(&Bs[(wn + cl + i * 16) * 32 + ko]);
#pragma unroll
    for (int mi = 0; mi < 4; mi++)
#pragma unroll
      for (int ni = 0; ni < 4; ni++)
        acc[mi][ni] = __builtin_amdgcn_mfma_f32_16x16x32_bf16(
            af[mi], bf[ni], acc[mi][ni], 0, 0, 0);
  }

  const int crow = (lane >> 4) * 4;
#pragma unroll
  for (int mi = 0; mi < 4; mi++) {
    const int mb = m0 + wm + mi * 16 + crow;
    const int bq = mb >> 11, sl = mb & 2047;
#pragma unroll
    for (int ni = 0; ni < 4; ni++) {
      const int n = n0 + wn + ni * 16 + cl;
      const int h = n / 192;
      const int rem = n - h * 192;
      const int cat = rem >> 6;  // 0=q 1=k 2=v (uniform per 16-col group)
      const int d = rem & 63;
      const float bv = bias[n];
      const size_t bh = (size_t)bq * 8 + h;
      if (cat == 2) {
        ushort4 o;
        o.x = f2bf(acc[mi][ni][0] + bv);
        o.y = f2bf(acc[mi][ni][1] + bv);
        o.z = f2bf(acc[mi][ni][2] + bv);
        o.w = f2bf(acc[mi][ni][3] + bv);
        *(ushort4*)(vtb + (bh * 64 + d) * 2048 + sl) = o;  // transposed V
      } else {
        __hip_bfloat16* dst = (cat == 0) ? qp : kpb;
        // q: 1/sqrt(64) * log2(e) -> scores directly in exp2 domain
        const float sc = (cat == 0) ? 0.18033688011112042f : 1.0f;
#pragma unroll
        for (int r = 0; r < 4; r++)
          dst[(bh * 2048 + sl + r) * 64 + d] =
              __float2bfloat16((acc[mi][ni][r] + bv) * sc);
      }
    }
  }
}

// ---------------- MFMA sliding-window attention ----------------
// block = (b,h, 64-query tile). Keys span [s0-128, s0+191] = 320 slots.
// Wave w owns q-rows [w*16, w*16+16): key tiles w..w+16. Only tiles 0 and 16
// (relative) can clip the window; interior tiles need only the pm addend.
__global__ __launch_bounds__(256) void attn_mfma(
    const __hip_bfloat16* __restrict__ qp, const __hip_bfloat16* __restrict__ kp,
    const __hip_bfloat16* __restrict__ vt, const int* __restrict__ pm,
    __hip_bfloat16* __restrict__ vals) {
  __shared__ __hip_bfloat16 sKP[320 * 72];  // K tile; later P (4x16x328, aliased)
  __shared__ float sCM[320];                // pm/range addend: 0 or -3e38

  const int tid = threadIdx.x, wave = tid >> 6, lane = tid & 63;
  const int bid = blockIdx.x;
  const int s0 = (bid & 31) * 64;
  const int bh = bid >> 5;
  const int b = bh >> 3, h = bh & 7;
  const int t0 = s0 - 128;
  const int cl = lane & 15;
  const int g4 = (lane >> 4) * 4;   // C-layout row base
  const int ko = (lane >> 4) * 8;   // A/B-frag k offset

  // stage K tile: 320 rows x 128B, 8 threads/row x 16B, coalesced
  {
    const int e = (tid & 7) * 8;
#pragma unroll
    for (int i = 0; i < 10; i++) {
      int row = (tid >> 3) + i * 32;
      int t = t0 + row; t = min(max(t, 0), 2047);
      *(uint4*)(&sKP[row * 72 + e]) =
          *(const uint4*)(kp + ((size_t)bh * 2048 + t) * 64 + e);
    }
  }
  for (int c = tid; c < 320; c += 256) {
    int t = t0 + c;
    bool ok = (t >= 0 && t < 2048) && (pm[b * 2048 + t] != 0);
    sCM[c] = ok ? 0.0f : -3.0e38f;
  }
  __syncthreads();

  // Q A-frags straight from global (16B/lane, L2-hot)
  const __hip_bfloat16* qrow =
      qp + ((size_t)bh * 2048 + s0 + wave * 16 + cl) * 64 + ko;
  bf16x8 aq0 = *(const bf16x8*)(qrow);
  bf16x8 aq1 = *(const bf16x8*)(qrow + 32);

  // QK^T: 17 key tiles x 2 k-steps
  f32x4 acc[17];
#pragma unroll
  for (int i = 0; i < 17; i++) {
    const int krow = (wave + i) * 16 + cl;
    bf16x8 b0 = *(const bf16x8*)(&sKP[krow * 72 + ko]);
    bf16x8 b1 = *(const bf16x8*)(&sKP[krow * 72 + ko + 32]);
    f32x4 z = {};
    z = __builtin_amdgcn_mfma_f32_16x16x32_bf16(aq0, b0, z, 0, 0, 0);
    acc[i] = __builtin_amdgcn_mfma_f32_16x16x32_bf16(aq1, b1, z, 0, 0, 0);
  }

  // mask + row max. Interior tiles: pm addend only (window holds structurally).
  float mrow[4] = {-3.0e38f, -3.0e38f, -3.0e38f, -3.0e38f};
#pragma unroll
  for (int i = 0; i < 17; i++) {
    const float ca = sCM[(wave + i) * 16 + cl];
#pragma unroll
    for (int r = 0; r < 4; r++) {
      float sv = acc[i][r] + ca;
      if (i == 0) {                      // dlt = cl - (g4+r) may be < 0
        if (cl < g4 + r) sv = -3.0e38f;
      } else if (i == 16) {              // dlt = 256 + cl - (g4+r) may be > 256
        if (cl > g4 + r) sv = -3.0e38f;
      }
      acc[i][r] = sv;
      mrow[r] = fmaxf(mrow[r], sv);
    }
  }
#pragma unroll
  for (int r = 0; r < 4; r++)
#pragma unroll
    for (int off = 1; off < 16; off <<= 1)
      mrow[r] = fmaxf(mrow[r], __shfl_xor(mrow[r], off));

  float lsum[4] = {0.f, 0.f, 0.f, 0.f};
#pragma unroll
  for (int i = 0; i < 17; i++)
#pragma unroll
    for (int r = 0; r < 4; r++) {
      float p = exp2f(acc[i][r] - mrow[r]);  // masked -> exact 0
      acc[i][r] = p;
      lsum[r] += p;
    }
#pragma unroll
  for (int r = 0; r < 4; r++)
#pragma unroll
    for (int off = 1; off < 16; off <<= 1)
      lsum[r] += __shfl_xor(lsum[r], off);

  __syncthreads();  // all waves done reading sK -> safe to alias P over it

  // write P (bf16) into per-wave 16x328 region
  __hip_bfloat16* sp = sKP + wave * 5248;
#pragma unroll
  for (int i = 0; i < 17; i++) {
    const int c = (wave + i) * 16 + cl;
#pragma unroll
    for (int r = 0; r < 4; r++)
      sp[(g4 + r) * 328 + c] = __float2bfloat16(acc[i][r]);
  }
  {  // zero the one extra tile the 32-aligned PV k-steps touch
    const int zt = (wave & 1) ? (wave - 1) : (wave + 17);
    const int zc = zt * 16 + cl;
#pragma unroll
    for (int r = 0; r < 4; r++)
      sp[(g4 + r) * 328 + zc] = __float2bfloat16(0.f);
  }
  __syncthreads();

  // PV: 9 k-steps of 32 keys; B-frags from transposed V in global (16B/lane)
  f32x4 oacc[4] = {};
  const int k0 = wave >> 1;
  const __hip_bfloat16* vbase = vt + (size_t)bh * 64 * 2048;
#pragma unroll
  for (int ks = 0; ks < 9; ks++) {
    const int kk = (k0 + ks) * 32 + ko;
    bf16x8 pa = *(const bf16x8*)(&sp[cl * 328 + kk]);
    int tv = t0 + kk; tv = min(max(tv, 0), 2040);
#pragma unroll
    for (int ni = 0; ni < 4; ni++) {
      const int d = ni * 16 + cl;
      bf16x8 vb = *(const bf16x8*)(vbase + (size_t)d * 2048 + tv);
      oacc[ni] = __builtin_amdgcn_mfma_f32_16x16x32_bf16(pa, vb, oacc[ni], 0, 0, 0);
    }
  }

  // epilogue: /l, pm-zero, store vals[s][h*64+d]
#pragma unroll
  for (int r = 0; r < 4; r++) {
    float linv = 1.0f / fmaxf(lsum[r], 1e-20f);
    const int qr = wave * 16 + g4 + r;
    if (sCM[qr + 128] != 0.0f) linv = 0.0f;  // fully-masked query -> 0
    const size_t obase = ((size_t)(b * 2048 + s0 + qr)) * 512 + h * 64 + cl;
#pragma unroll
    for (int ni = 0; ni < 4; ni++)
      vals[obase + ni * 16] = __float2bfloat16(oacc[ni][r] * linv);
  }
}

// ---------------- output projection GEMM (64x128 tile, lds-dma, f32 out) ----
__global__ __launch_bounds__(256) void gemm_out(
    const __hip_bfloat16* __restrict__ A, const __hip_bfloat16* __restrict__ Bw,
    const float* __restrict__ bias, float* __restrict__ C) {
  __shared__ __hip_bfloat16 As[64 * 32];
  __shared__ __hip_bfloat16 Bs[128 * 32];

  const int tid = threadIdx.x, wave = tid >> 6, lane = tid & 63;
  const int m0 = blockIdx.x * 64, n0 = blockIdx.y * 128;
  const int wm = (wave >> 1) * 32, wn = (wave & 1) * 64;
  const int cl = lane & 15, ko = (lane >> 4) * 8;
  const int srow = wave * 16 + (lane >> 2);
  const int scol = (lane & 3) * 8;

  f32x4 acc[2][4] = {};

  for (int k0 = 0; k0 < 512; k0 += 32) {
    __syncthreads();
    ldsdma16(&As[wave * 512],        A  + (size_t)(m0 + srow) * 512 + k0 + scol);
    ldsdma16(&Bs[wave * 512],        Bw + (size_t)(n0 + srow) * 512 + k0 + scol);
    ldsdma16(&Bs[2048 + wave * 512], Bw + (size_t)(n0 + 64 + srow) * 512 + k0 + scol);
    __syncthreads();

    bf16x8 af[2], bf[4];
#pragma unroll
    for (int i = 0; i < 2; i++)
      af[i] = *(const bf16x8*)(&As[(wm + cl + i * 16) * 32 + ko]);
#pragma unroll
    for (int i = 0; i < 4; i++)
      bf[i] = *(const bf16x8*)(&Bs[(wn + cl + i * 16) * 32 + ko]);
#pragma unroll
    for (int mi = 0; mi < 2; mi++)
#pragma unroll
      for (int ni = 0; ni < 4; ni++)
        acc[mi][ni] = __builtin_amdgcn_mfma_f32_16x16x32_bf16(
            af[mi], bf[ni], acc[mi][ni], 0, 0, 0);
  }

  const int crow = (lane >> 4) * 4;
#pragma unroll
  for (int mi = 0; mi < 2; mi++) {
#pragma unroll
    for (int ni = 0; ni < 4; ni++) {
      const int n = n0 + wn + ni * 16 + cl;
      const float bv = bias[n];
      const int mb = m0 + wm + mi * 16 + crow;
#pragma unroll
      for (int r = 0; r < 4; r++)
        C[(size_t)(mb + r) * 512 + n] = acc[mi][ni][r] + bv;
    }
  }
}

extern "C" void kernel_launch(void* const* d_in, const int* in_sizes, int n_in,
                              void* d_out, int out_size, void* d_ws, size_t ws_size,
                              hipStream_t stream) {
  const float* x     = (const float*)d_in[0];   // (2,2048,512)
  const int*   pm    = (const int*)d_in[1];     // (2,2048)
  const float* qkv_w = (const float*)d_in[2];   // (1536,512)
  const float* qkv_b = (const float*)d_in[3];   // (1536,)
  const float* o_w   = (const float*)d_in[4];   // (512,512)
  const float* o_b   = (const float*)d_in[5];   // (512,)
  float* out = (float*)d_out;                   // (2,2048,512)

  __hip_bfloat16* wsb   = (__hip_bfloat16*)d_ws;
  __hip_bfloat16* xb    = wsb;               // 2097152
  __hip_bfloat16* wqkvb = wsb + 2097152;     // 786432
  __hip_bfloat16* wob   = wsb + 2883584;     // 262144
  __hip_bfloat16* qp    = wsb + 3145728;     // 2097152  [bh][s][64] (scaled)
  __hip_bfloat16* kp    = wsb + 5242880;     // 2097152  [bh][s][64]
  __hip_bfloat16* vt    = wsb + 7340032;     // 2097152  [bh][d][2048]
  __hip_bfloat16* vals  = wsb + 9437184;     // 2097152  [s][512]

  dim3 blk(256);
  cvt3_kernel<<<dim3(3072), blk, 0, stream>>>(
      x, (unsigned short*)xb, 2097152,
      qkv_w, (unsigned short*)wqkvb, 786432,
      o_w, (unsigned short*)wob, 262144);
  gemm_qkv<<<dim3(32, 12), blk, 0, stream>>>(
      xb, wqkvb, qkv_b, qp, kp, (unsigned short*)vt);
  attn_mfma<<<dim3(512), blk, 0, stream>>>(qp, kp, vt, pm, vals);
  gemm_out<<<dim3(64, 4), blk, 0, stream>>>(vals, wob, o_b, out);
}